// Round 10
// baseline (346.861 us; speedup 1.0000x reference)
//
#include <hip/hip_runtime.h>
#include <math.h>

#define NEG_SLOPE 0.2f
#define BSHIFT 8            // 256 nodes per bucket
#define MAXBUK 512          // supports N up to 131072

typedef __attribute__((ext_vector_type(8))) short short8;   // 8 bf16 (MFMA A/B frag)
typedef __attribute__((ext_vector_type(4))) float floatx4;  // MFMA C/D frag

static __device__ __forceinline__ float lrelu_exp(float e) {
    e = fmaxf(e, NEG_SLOPE * e);
    return __expf(e);
}

// fp32 -> bf16 (round-to-nearest-even)
static __device__ __forceinline__ short f2bf(float f) {
    union { float f; unsigned u; } v; v.f = f;
    unsigned r = v.u + 0x7FFFu + ((v.u >> 16) & 1u);
    return (short)(r >> 16);
}
// bf16 bits -> fp32 (exact)
static __device__ __forceinline__ float bf2f(unsigned short s) {
    union { float f; unsigned u; } v;
    v.u = ((unsigned)s) << 16;
    return v.f;
}
// packed pair of bf16 -> two fp32 (1 shift / 1 and)
static __device__ __forceinline__ float bfpair_lo(unsigned v) {
    union { float f; unsigned u; } x; x.u = v << 16; return x.f;
}
static __device__ __forceinline__ float bfpair_hi(unsigned v) {
    union { float f; unsigned u; } x; x.u = v & 0xffff0000u; return x.f;
}
// split f into hi+lo bf16 pair (covers ~16 mantissa bits)
static __device__ __forceinline__ void splitbf(float f, short& hi, short& lo) {
    hi = f2bf(f);
    lo = f2bf(f - bf2f((unsigned short)hi));
}

// ================= CSR build: LDS-bucketed partition (no global data atomics) =================

__global__ __launch_bounds__(256) void k_hist(const int* __restrict__ dst, int E, int CHUNK,
                                              int NBLK, int NBUK, int* __restrict__ blockhist) {
    __shared__ int hist[MAXBUK];
    int t = threadIdx.x, b = blockIdx.x;
    for (int i = t; i < NBUK; i += 256) hist[i] = 0;
    __syncthreads();
    int e0 = b * CHUNK, e1 = e0 + CHUNK; if (e1 > E) e1 = E;
    for (int e = e0 + t; e < e1; e += 256) atomicAdd(&hist[dst[e] >> BSHIFT], 1);
    __syncthreads();
    for (int i = t; i < NBUK; i += 256) blockhist[i * NBLK + b] = hist[i];
}

__global__ __launch_bounds__(512) void k_bucket_scan(const int* __restrict__ blockhist,
                                                     int* __restrict__ bucketbase,
                                                     int NBLK, int NBUK) {
    __shared__ int sh[512];
    int t = threadIdx.x;
    int tot = 0;
    if (t < NBUK) {
        const int* p = blockhist + (size_t)t * NBLK;
        for (int k = 0; k < NBLK; ++k) tot += p[k];
    }
    sh[t] = tot;
    __syncthreads();
#pragma unroll
    for (int o = 1; o < 512; o <<= 1) {
        int u = (t >= o) ? sh[t - o] : 0;
        __syncthreads();
        sh[t] += u;
        __syncthreads();
    }
    if (t < NBUK) bucketbase[t] = sh[t] - tot;
    if (t == NBUK - 1) bucketbase[NBUK] = sh[t];
}

__global__ __launch_bounds__(256) void k_colscan(int* __restrict__ blockhist,
                                                 const int* __restrict__ bucketbase,
                                                 int NBLK) {
    int bucket = blockIdx.x, t = threadIdx.x;
    int v = (t < NBLK) ? blockhist[(size_t)bucket * NBLK + t] : 0;
    int lane = t & 63, wv = t >> 6;
    int s = v;
#pragma unroll
    for (int o = 1; o < 64; o <<= 1) {
        int u = __shfl_up(s, o, 64);
        if (lane >= o) s += u;
    }
    __shared__ int wsum[4];
    if (lane == 63) wsum[wv] = s;
    __syncthreads();
    int base = 0;
#pragma unroll
    for (int w = 0; w < 4; ++w) base += (w < wv) ? wsum[w] : 0;
    int excl = s + base - v + bucketbase[bucket];
    if (t < NBLK) blockhist[(size_t)bucket * NBLK + t] = excl;
}

// packed record: (src << 8) | (dst & 255)   [src < 2^24; bucket id recovers dst high bits]
__global__ __launch_bounds__(256) void k_partition(const int* __restrict__ src,
                                                   const int* __restrict__ dst, int E, int CHUNK,
                                                   int NBLK, int NBUK,
                                                   const int* __restrict__ blockhist,
                                                   unsigned* __restrict__ packed) {
    __shared__ int cur[MAXBUK];
    int t = threadIdx.x, b = blockIdx.x;
    for (int i = t; i < NBUK; i += 256) cur[i] = blockhist[(size_t)i * NBLK + b];
    __syncthreads();
    int e0 = b * CHUNK, e1 = e0 + CHUNK; if (e1 > E) e1 = E;
    for (int e = e0 + t; e < e1; e += 256) {
        int d = dst[e], s = src[e];
        int pos = atomicAdd(&cur[d >> BSHIFT], 1);
        packed[pos] = ((unsigned)s << 8) | ((unsigned)d & 255u);
    }
}

__global__ __launch_bounds__(256) void k_fine(const unsigned* __restrict__ packed,
                                              const int* __restrict__ bucketbase,
                                              int* __restrict__ offsets,
                                              int* __restrict__ csr_src,
                                              int N, int NBUK) {
    __shared__ int fcnt[256];
    __shared__ int wsum[4];
    int bucket = blockIdx.x, t = threadIdx.x;
    int lo = bucket << BSHIFT;
    int nn = N - lo; if (nn > 256) nn = 256;
    int ebase = bucketbase[bucket];
    int ecnt = bucketbase[bucket + 1] - ebase;
    fcnt[t] = 0;
    __syncthreads();
    for (int i = t; i < ecnt; i += 256) {
        unsigned p = packed[ebase + i];
        atomicAdd(&fcnt[p & 255u], 1);
    }
    __syncthreads();
    int v = fcnt[t];
    int lane = t & 63, wv = t >> 6;
    int s = v;
#pragma unroll
    for (int o = 1; o < 64; o <<= 1) {
        int u = __shfl_up(s, o, 64);
        if (lane >= o) s += u;
    }
    if (lane == 63) wsum[wv] = s;
    __syncthreads();
    int base = 0;
#pragma unroll
    for (int w = 0; w < 4; ++w) base += (w < wv) ? wsum[w] : 0;
    int excl = s + base - v;
    if (t < nn) offsets[lo + t] = ebase + excl;
    if (bucket == NBUK - 1 && t == 0) offsets[N] = ebase + ecnt;  // == E
    __syncthreads();
    fcnt[t] = excl;   // reuse as cursor
    __syncthreads();
    for (int i = t; i < ecnt; i += 256) {
        unsigned p = packed[ebase + i];
        int pos = atomicAdd(&fcnt[p & 255u], 1);
        csr_src[ebase + pos] = (int)(p >> 8);
    }
}

// ---------------- W2 pre-split: hi/lo bf16, padded 40 -> 48 cols ----------------
__global__ __launch_bounds__(256) void k_splitW2(const float* __restrict__ W2,
                                                 short* __restrict__ w2h,
                                                 short* __restrict__ w2l) {
    int i = blockIdx.x * 256 + threadIdx.x;
    if (i < 64 * 48) {
        int row = i / 48, col = i % 48;
        short hi = 0, lo = 0;
        if (col < 40) splitbf(W2[row * 40 + col], hi, lo);
        w2h[i] = hi; w2l[i] = lo;
    }
}

// ---------------- Layer 1 GEMM via MFMA bf16 (plain; inputs replay-constant) ----------------
__global__ __launch_bounds__(256) void k_gemm1(const float* __restrict__ x,
                                               const float* __restrict__ W1,
                                               const float* __restrict__ att_s,
                                               const float* __restrict__ att_d,
                                               unsigned short* __restrict__ h1b,
                                               float* __restrict__ a_s1,
                                               float* __restrict__ a_d1, int N) {
    int tid = threadIdx.x, wave = tid >> 6, lane = tid & 63;
    int n16 = lane & 15, q = lane >> 4;
    int nb = blockIdx.x * 64 + wave * 16;
    if (nb >= N) return;

    short8 bfr[4][4];
#pragma unroll
    for (int ct = 0; ct < 4; ++ct) {
        int n = ct * 16 + n16;
#pragma unroll
        for (int kc = 0; kc < 4; ++kc) {
            int k0 = kc * 32 + q * 8;
            short8 b;
#pragma unroll
            for (int j = 0; j < 8; ++j) b[j] = f2bf(W1[(k0 + j) * 64 + n]);
            bfr[ct][kc] = b;
        }
    }

    int arow = nb + n16; if (arow >= N) arow = N - 1;
    const float* xr = x + (size_t)arow * 128 + q * 8;
    short8 afr[4];
#pragma unroll
    for (int kc = 0; kc < 4; ++kc) {
        float4 u0 = *(const float4*)(xr + kc * 32);
        float4 u1 = *(const float4*)(xr + kc * 32 + 4);
        short8 a;
        a[0] = f2bf(u0.x); a[1] = f2bf(u0.y); a[2] = f2bf(u0.z); a[3] = f2bf(u0.w);
        a[4] = f2bf(u1.x); a[5] = f2bf(u1.y); a[6] = f2bf(u1.z); a[7] = f2bf(u1.w);
        afr[kc] = a;
    }

    floatx4 acc[4];
#pragma unroll
    for (int ct = 0; ct < 4; ++ct) {
        floatx4 c = {0.f, 0.f, 0.f, 0.f};
#pragma unroll
        for (int kc = 0; kc < 4; ++kc)
            c = __builtin_amdgcn_mfma_f32_16x16x32_bf16(afr[kc], bfr[ct][kc], c, 0, 0, 0);
        acc[ct] = c;
    }

#pragma unroll
    for (int ct = 0; ct < 4; ++ct) {
#pragma unroll
        for (int r = 0; r < 4; ++r) {
            int row = nb + q * 4 + r;
            if (row < N) h1b[(size_t)row * 64 + ct * 16 + n16] = (unsigned short)f2bf(acc[ct][r]);
        }
    }

#pragma unroll
    for (int ct = 0; ct < 4; ++ct) {
        float as = att_s[ct * 16 + n16];
        float ad = att_d[ct * 16 + n16];
#pragma unroll
        for (int r = 0; r < 4; ++r) {
            float ps = acc[ct][r] * as;
            float pd = acc[ct][r] * ad;
#pragma unroll
            for (int m = 1; m < 8; m <<= 1) {
                ps += __shfl_xor(ps, m, 64);
                pd += __shfl_xor(pd, m, 64);
            }
            int row = nb + q * 4 + r;
            if ((n16 & 7) == 0 && row < N) {
                int h = 2 * ct + (n16 >> 3);
                a_s1[row * 8 + h] = ps;
                a_d1[row * 8 + h] = pd;
            }
        }
    }
}

// ---------------- Layer 1 aggregation: 8 edges per gather instr, 1 head per lane ------------
// lane = (eg, cb): edge-slot eg = lane>>3 (8 edges in parallel), cb = lane&7 = channel block
// AND head index (channels cb*8..cb*8+7 all belong to head cb). Each lane: one 16B row gather
// + one exp per (edge, head) — zero redundant exp; 8 rows per wave load instruction.
__global__ __launch_bounds__(256) void k_agg1(const unsigned short* __restrict__ h1b,
                                              const float* __restrict__ a_s1,
                                              const float* __restrict__ a_d1,
                                              const int* __restrict__ offsets,
                                              const int* __restrict__ csr_src,
                                              const float* __restrict__ b1,
                                              float* __restrict__ y1, int N) {
    int wave = threadIdx.x >> 6, lane = threadIdx.x & 63;
    int d = blockIdx.x * 4 + wave;
    if (d >= N) return;
    int eg = lane >> 3;          // edge slot 0..7
    int cb = lane & 7;           // channel block == head
    float ad = a_d1[d * 8 + cb];
    float acc[8] = {0.f, 0.f, 0.f, 0.f, 0.f, 0.f, 0.f, 0.f};
    float wsum = 0.f;
    if (eg == 0) {               // self-loop handled by edge-group 0
        float w0 = lrelu_exp(a_s1[d * 8 + cb] + ad);
        uint4 r = *(const uint4*)(h1b + (size_t)d * 64 + cb * 8);
        wsum = w0;
        acc[0] = w0 * bfpair_lo(r.x); acc[1] = w0 * bfpair_hi(r.x);
        acc[2] = w0 * bfpair_lo(r.y); acc[3] = w0 * bfpair_hi(r.y);
        acc[4] = w0 * bfpair_lo(r.z); acc[5] = w0 * bfpair_hi(r.z);
        acc[6] = w0 * bfpair_lo(r.w); acc[7] = w0 * bfpair_hi(r.w);
    }
    int i0 = offsets[d], i1 = offsets[d + 1];
    for (int base = i0; base < i1; base += 64) {
        int m = i1 - base; if (m > 64) m = 64;
        int sv = (lane < m) ? csr_src[base + lane] : 0;
        for (int j = 0; j < m; j += 16) {
            int e0 = j + eg, e1 = j + 8 + eg;
            int s0 = __shfl(sv, e0, 64), s1 = __shfl(sv, e1, 64);
            bool ok0 = e0 < m, ok1 = e1 < m;
            if (!ok0) s0 = 0;
            if (!ok1) s1 = 0;
            float ev0 = a_s1[s0 * 8 + cb] + ad;
            float ev1 = a_s1[s1 * 8 + cb] + ad;
            uint4 r0 = *(const uint4*)(h1b + (size_t)s0 * 64 + cb * 8);
            uint4 r1 = *(const uint4*)(h1b + (size_t)s1 * 64 + cb * 8);
            float w0 = ok0 ? lrelu_exp(ev0) : 0.f;
            float w1 = ok1 ? lrelu_exp(ev1) : 0.f;
            wsum += w0 + w1;
            acc[0] = fmaf(w0, bfpair_lo(r0.x), acc[0]); acc[1] = fmaf(w0, bfpair_hi(r0.x), acc[1]);
            acc[2] = fmaf(w0, bfpair_lo(r0.y), acc[2]); acc[3] = fmaf(w0, bfpair_hi(r0.y), acc[3]);
            acc[4] = fmaf(w0, bfpair_lo(r0.z), acc[4]); acc[5] = fmaf(w0, bfpair_hi(r0.z), acc[5]);
            acc[6] = fmaf(w0, bfpair_lo(r0.w), acc[6]); acc[7] = fmaf(w0, bfpair_hi(r0.w), acc[7]);
            acc[0] = fmaf(w1, bfpair_lo(r1.x), acc[0]); acc[1] = fmaf(w1, bfpair_hi(r1.x), acc[1]);
            acc[2] = fmaf(w1, bfpair_lo(r1.y), acc[2]); acc[3] = fmaf(w1, bfpair_hi(r1.y), acc[3]);
            acc[4] = fmaf(w1, bfpair_lo(r1.z), acc[4]); acc[5] = fmaf(w1, bfpair_hi(r1.z), acc[5]);
            acc[6] = fmaf(w1, bfpair_lo(r1.w), acc[6]); acc[7] = fmaf(w1, bfpair_hi(r1.w), acc[7]);
        }
    }
    // reduce over the 8 edge groups (strides 8,16,32); every lane ends with full sums
#pragma unroll
    for (int s = 8; s < 64; s <<= 1) {
        wsum += __shfl_xor(wsum, s, 64);
#pragma unroll
        for (int k = 0; k < 8; ++k) acc[k] += __shfl_xor(acc[k], s, 64);
    }
    if (eg == 0) {
        float inv = 1.f / (wsum + 1e-16f);
        float o[8];
#pragma unroll
        for (int k = 0; k < 8; ++k) {
            float v = acc[k] * inv + b1[cb * 8 + k];
            o[k] = v > 0.f ? v : expm1f(v);   // ELU
        }
        float4 lo4 = make_float4(o[0], o[1], o[2], o[3]);
        float4 hi4 = make_float4(o[4], o[5], o[6], o[7]);
        *(float4*)(y1 + (size_t)d * 64 + cb * 8)     = lo4;   // fp32 (precision-critical)
        *(float4*)(y1 + (size_t)d * 64 + cb * 8 + 4) = hi4;
    }
}

// ---------------- Layer 2 GEMM, split-bf16 (y1 replay-variant -> fp32-class needed) ----------
__global__ __launch_bounds__(256) void k_gemm2(const float* __restrict__ y1,
                                               const short* __restrict__ w2h,
                                               const short* __restrict__ w2l,
                                               const float* __restrict__ att_s,
                                               const float* __restrict__ att_d,
                                               unsigned short* __restrict__ h2b,
                                               float* __restrict__ a2s,
                                               float* __restrict__ a2d, int N) {
    int tid = threadIdx.x, wave = tid >> 6, lane = tid & 63;
    int n16 = lane & 15, q = lane >> 4;
    int nb = blockIdx.x * 64 + wave * 16;
    if (nb >= N) return;

    int arow = nb + n16; if (arow >= N) arow = N - 1;
    const float* yr = y1 + (size_t)arow * 64 + q * 8;
    short8 ah[2], al[2];
#pragma unroll
    for (int kc = 0; kc < 2; ++kc) {
        float4 u0 = *(const float4*)(yr + kc * 32);
        float4 u1 = *(const float4*)(yr + kc * 32 + 4);
        short8 h, l; short hi, lo;
        splitbf(u0.x, hi, lo); h[0] = hi; l[0] = lo;
        splitbf(u0.y, hi, lo); h[1] = hi; l[1] = lo;
        splitbf(u0.z, hi, lo); h[2] = hi; l[2] = lo;
        splitbf(u0.w, hi, lo); h[3] = hi; l[3] = lo;
        splitbf(u1.x, hi, lo); h[4] = hi; l[4] = lo;
        splitbf(u1.y, hi, lo); h[5] = hi; l[5] = lo;
        splitbf(u1.z, hi, lo); h[6] = hi; l[6] = lo;
        splitbf(u1.w, hi, lo); h[7] = hi; l[7] = lo;
        ah[kc] = h; al[kc] = l;
    }

    float psr[4] = {0.f, 0.f, 0.f, 0.f}, pdr[4] = {0.f, 0.f, 0.f, 0.f};
#pragma unroll
    for (int ct = 0; ct < 3; ++ct) {
        int n = ct * 16 + n16;
        short8 bh0, bh1, bl0, bl1;
#pragma unroll
        for (int j = 0; j < 8; ++j) {
            int k0 = q * 8 + j;
            bh0[j] = w2h[k0 * 48 + n];
            bl0[j] = w2l[k0 * 48 + n];
            bh1[j] = w2h[(32 + k0) * 48 + n];
            bl1[j] = w2l[(32 + k0) * 48 + n];
        }
        floatx4 c = {0.f, 0.f, 0.f, 0.f};
        c = __builtin_amdgcn_mfma_f32_16x16x32_bf16(ah[0], bl0, c, 0, 0, 0);
        c = __builtin_amdgcn_mfma_f32_16x16x32_bf16(al[0], bh0, c, 0, 0, 0);
        c = __builtin_amdgcn_mfma_f32_16x16x32_bf16(ah[0], bh0, c, 0, 0, 0);
        c = __builtin_amdgcn_mfma_f32_16x16x32_bf16(ah[1], bl1, c, 0, 0, 0);
        c = __builtin_amdgcn_mfma_f32_16x16x32_bf16(al[1], bh1, c, 0, 0, 0);
        c = __builtin_amdgcn_mfma_f32_16x16x32_bf16(ah[1], bh1, c, 0, 0, 0);

        int col = ct * 16 + n16;
#pragma unroll
        for (int r = 0; r < 4; ++r) {
            int row = nb + q * 4 + r;
            if (col < 40 && row < N) h2b[(size_t)row * 40 + col] = (unsigned short)f2bf(c[r]);
        }
        float asv = (col < 40) ? att_s[col] : 0.f;
        float adv = (col < 40) ? att_d[col] : 0.f;
#pragma unroll
        for (int r = 0; r < 4; ++r) {
            psr[r] = fmaf(c[r], asv, psr[r]);
            pdr[r] = fmaf(c[r], adv, pdr[r]);
        }
    }
#pragma unroll
    for (int r = 0; r < 4; ++r) {
        float ps = psr[r], pd = pdr[r];
#pragma unroll
        for (int m = 1; m < 16; m <<= 1) {
            ps += __shfl_xor(ps, m, 64);
            pd += __shfl_xor(pd, m, 64);
        }
        int row = nb + q * 4 + r;
        if (n16 == 0 && row < N) { a2s[row] = ps; a2d[row] = pd; }
    }
}

// ---------------- Layer 2 aggregation: 3 edges per gather instr + log_softmax ----------------
__global__ __launch_bounds__(256) void k_agg2(const unsigned short* __restrict__ h2b,
                                              const float* __restrict__ a2s,
                                              const float* __restrict__ a2d,
                                              const int* __restrict__ offsets,
                                              const int* __restrict__ csr_src,
                                              const float* __restrict__ b2,
                                              float* __restrict__ out, int N) {
    int wave = threadIdx.x >> 6, lane = threadIdx.x & 63;
    int d = blockIdx.x * 4 + wave;
    if (d >= N) return;
    int t = lane / 20;          // 0..2 active thirds (3 = idle tail lanes 60..63)
    int c = lane % 20;          // channel pair: 2c, 2c+1
    float ad = a2d[d];
    float w0 = lrelu_exp(a2s[d] + ad);
    float accx = 0.f, accy = 0.f;
    if (t == 0) {               // self-loop on third 0
        unsigned v = *(const unsigned*)(h2b + (size_t)d * 40 + 2 * c);
        accx = w0 * bfpair_lo(v);
        accy = w0 * bfpair_hi(v);
    }
    float wsum_l = 0.f;
    int i0 = offsets[d], i1 = offsets[d + 1];
    for (int base = i0; base < i1; base += 48) {
        int m = i1 - base; if (m > 48) m = 48;
        int sv = 0; float wv = 0.f;
        if (lane < m) {
            sv = csr_src[base + lane];
            wv = lrelu_exp(a2s[sv] + ad);
        }
        wsum_l += wv;
        for (int j = 0; j < m; j += 24) {
            int si[8]; float wq[8]; unsigned vv[8];
#pragma unroll
            for (int u = 0; u < 8; ++u) {
                int e = j + 3 * u + t;
                si[u] = __shfl(sv, e, 64);
                wq[u] = __shfl(wv, e, 64);
            }
#pragma unroll
            for (int u = 0; u < 8; ++u)
                vv[u] = *(const unsigned*)(h2b + (size_t)si[u] * 40 + 2 * c);
#pragma unroll
            for (int u = 0; u < 8; ++u) {
                accx = fmaf(wq[u], bfpair_lo(vv[u]), accx);
                accy = fmaf(wq[u], bfpair_hi(vv[u]), accy);
            }
        }
    }
    accx += __shfl(accx, lane + 20, 64) + __shfl(accx, lane + 40, 64);
    accy += __shfl(accy, lane + 20, 64) + __shfl(accy, lane + 40, 64);
#pragma unroll
    for (int mm = 1; mm < 64; mm <<= 1) wsum_l += __shfl_xor(wsum_l, mm, 64);
    float wsum = wsum_l + w0;
    bool act = (lane < 20);
    float inv = 1.f / (wsum + 1e-16f);
    float ox = act ? (accx * inv + b2[2 * c]) : -INFINITY;
    float oy = act ? (accy * inv + b2[2 * c + 1]) : -INFINITY;
    float mx = fmaxf(ox, oy);
#pragma unroll
    for (int mm = 1; mm < 64; mm <<= 1) mx = fmaxf(mx, __shfl_xor(mx, mm, 64));
    float ex = act ? (__expf(ox - mx) + __expf(oy - mx)) : 0.f;
#pragma unroll
    for (int mm = 1; mm < 64; mm <<= 1) ex += __shfl_xor(ex, mm, 64);
    if (act) {
        float lse = __logf(ex);
        float2 o2 = make_float2(ox - mx - lse, oy - mx - lse);
        *(float2*)(out + (size_t)d * 40 + 2 * c) = o2;
    }
}

// ---------------- launcher ----------------

extern "C" void kernel_launch(void* const* d_in, const int* in_sizes, int n_in,
                              void* d_out, int out_size, void* d_ws, size_t ws_size,
                              hipStream_t stream) {
    const float* x   = (const float*)d_in[0];
    const int*   ei  = (const int*)d_in[1];
    const float* W1  = (const float*)d_in[2];
    const float* as1 = (const float*)d_in[3];
    const float* ad1 = (const float*)d_in[4];
    const float* b1  = (const float*)d_in[5];
    const float* W2  = (const float*)d_in[6];
    const float* as2 = (const float*)d_in[7];
    const float* ad2 = (const float*)d_in[8];
    const float* b2  = (const float*)d_in[9];
    float* out = (float*)d_out;

    int N = in_sizes[0] / 128;   // 100000
    int E = in_sizes[1] / 2;     // 1600000
    const int* src = ei;
    const int* dst = ei + E;

    int NBUK = (N + 255) >> BSHIFT;          // 391
    int CHUNK = 8192;
    while ((E + CHUNK - 1) / CHUNK > 256) CHUNK <<= 1;
    int NBLK = (E + CHUNK - 1) / CHUNK;      // 196

    char* ws = (char*)d_ws;
    size_t off = 0;
    auto alloc = [&](size_t bytes) -> char* {
        char* p = ws + off;
        off += (bytes + 255) & ~(size_t)255;
        return p;
    };
    unsigned short* h1b = (unsigned short*)alloc((size_t)N * 64 * 2);   // bf16
    float* a_s1    = (float*)alloc((size_t)N * 8 * 4);
    float* a_d1    = (float*)alloc((size_t)N * 8 * 4);
    float* y1      = (float*)alloc((size_t)N * 64 * 4);                 // fp32 (precision-critical)
    // h2b (bf16, 8 MB) and packed (uint, 6.4 MB) are temporally disjoint: share region.
    size_t shared_sz = (size_t)N * 40 * 2;
    if ((size_t)E * 4 > shared_sz) shared_sz = (size_t)E * 4;
    char*  region  = alloc(shared_sz);
    unsigned short* h2b = (unsigned short*)region;
    unsigned* packed    = (unsigned*)region;
    float* a2s     = (float*)alloc((size_t)N * 4);
    float* a2d     = (float*)alloc((size_t)N * 4);
    int*   offsets = (int*)alloc((size_t)(N + 1) * 4);
    int*   csr_src = (int*)alloc((size_t)E * 4);
    int*   blockhist  = (int*)alloc((size_t)NBUK * NBLK * 4);
    int*   bucketbase = (int*)alloc((size_t)(NBUK + 1) * 4);
    short* w2h     = (short*)alloc((size_t)64 * 48 * 2);
    short* w2l     = (short*)alloc((size_t)64 * 48 * 2);

    int nb = (N + 3) / 4;
    int gb = (N + 63) / 64;

    k_hist<<<NBLK, 256, 0, stream>>>(dst, E, CHUNK, NBLK, NBUK, blockhist);
    k_bucket_scan<<<1, 512, 0, stream>>>(blockhist, bucketbase, NBLK, NBUK);
    k_colscan<<<NBUK, 256, 0, stream>>>(blockhist, bucketbase, NBLK);
    k_partition<<<NBLK, 256, 0, stream>>>(src, dst, E, CHUNK, NBLK, NBUK, blockhist, packed);
    k_fine<<<NBUK, 256, 0, stream>>>(packed, bucketbase, offsets, csr_src, N, NBUK);
    k_splitW2<<<12, 256, 0, stream>>>(W2, w2h, w2l);
    k_gemm1<<<gb, 256, 0, stream>>>(x, W1, as1, ad1, h1b, a_s1, a_d1, N);
    k_agg1<<<nb, 256, 0, stream>>>(h1b, a_s1, a_d1, offsets, csr_src, b1, y1, N);
    k_gemm2<<<gb, 256, 0, stream>>>(y1, w2h, w2l, as2, ad2, h2b, a2s, a2d, N);
    k_agg2<<<nb, 256, 0, stream>>>(h2b, a2s, a2d, offsets, csr_src, b2, out, N);
}

// Round 11
// 290.191 us; speedup vs baseline: 1.1953x; 1.1953x over previous
//
#include <hip/hip_runtime.h>
#include <math.h>

#define NEG_SLOPE 0.2f
#define BSHIFT 8            // 256 nodes per bucket
#define MAXBUK 512          // supports N up to 131072

typedef __attribute__((ext_vector_type(8))) short short8;   // 8 bf16 (MFMA A/B frag)
typedef __attribute__((ext_vector_type(4))) float floatx4;  // MFMA C/D frag

static __device__ __forceinline__ float lrelu_exp(float e) {
    e = fmaxf(e, NEG_SLOPE * e);
    return __expf(e);
}

// fp32 -> bf16 (round-to-nearest-even)
static __device__ __forceinline__ short f2bf(float f) {
    union { float f; unsigned u; } v; v.f = f;
    unsigned r = v.u + 0x7FFFu + ((v.u >> 16) & 1u);
    return (short)(r >> 16);
}
// bf16 bits -> fp32 (exact)
static __device__ __forceinline__ float bf2f(unsigned short s) {
    union { float f; unsigned u; } v;
    v.u = ((unsigned)s) << 16;
    return v.f;
}
// packed pair of bf16 -> two fp32 (1 shift / 1 and)
static __device__ __forceinline__ float bfpair_lo(unsigned v) {
    union { float f; unsigned u; } x; x.u = v << 16; return x.f;
}
static __device__ __forceinline__ float bfpair_hi(unsigned v) {
    union { float f; unsigned u; } x; x.u = v & 0xffff0000u; return x.f;
}
// split f into hi+lo bf16 pair (covers ~16 mantissa bits)
static __device__ __forceinline__ void splitbf(float f, short& hi, short& lo) {
    hi = f2bf(f);
    lo = f2bf(f - bf2f((unsigned short)hi));
}

// ================= CSR build: LDS-bucketed partition (no global data atomics) =================
// R11: 391 blocks x 512 threads for hist/partition (was 196x256 -> latency-bound);
// colscan is a carry-loop (any NBLK) writing per-bucket totals; bucket_scan only scans totals.

__global__ __launch_bounds__(512) void k_hist(const int* __restrict__ dst, int E, int CHUNK,
                                              int NBLK, int NBUK, int* __restrict__ blockhist) {
    __shared__ int hist[MAXBUK];
    int t = threadIdx.x, b = blockIdx.x;
    for (int i = t; i < NBUK; i += 512) hist[i] = 0;
    __syncthreads();
    int e0 = b * CHUNK, e1 = e0 + CHUNK; if (e1 > E) e1 = E;
    for (int e = e0 + t; e < e1; e += 512) atomicAdd(&hist[dst[e] >> BSHIFT], 1);
    __syncthreads();
    for (int i = t; i < NBUK; i += 512) blockhist[(size_t)i * NBLK + b] = hist[i];
}

// Per-bucket LOCAL exclusive scan across NBLK block-counts (carry loop), writes bucket total.
__global__ __launch_bounds__(256) void k_colscan(int* __restrict__ blockhist,
                                                 int* __restrict__ btot, int NBLK) {
    int bucket = blockIdx.x, t = threadIdx.x;
    int lane = t & 63, wv = t >> 6;
    __shared__ int wsum[4];
    __shared__ int carry_s;
    if (t == 0) carry_s = 0;
    __syncthreads();
    for (int base = 0; base < NBLK; base += 256) {
        int idx = base + t;
        int v = (idx < NBLK) ? blockhist[(size_t)bucket * NBLK + idx] : 0;
        int s = v;
#pragma unroll
        for (int o = 1; o < 64; o <<= 1) {
            int u = __shfl_up(s, o, 64);
            if (lane >= o) s += u;
        }
        if (lane == 63) wsum[wv] = s;
        __syncthreads();
        int b0 = 0;
#pragma unroll
        for (int w = 0; w < 4; ++w) b0 += (w < wv) ? wsum[w] : 0;
        int excl = s + b0 - v + carry_s;
        if (idx < NBLK) blockhist[(size_t)bucket * NBLK + idx] = excl;
        __syncthreads();
        if (t == 255) carry_s += s + b0;   // chunk total
        __syncthreads();
    }
    if (t == 0) btot[bucket] = carry_s;
}

// Exclusive scan over NBUK bucket totals (NBUK <= 512).
__global__ __launch_bounds__(512) void k_bucket_scan(const int* __restrict__ btot,
                                                     int* __restrict__ bucketbase, int NBUK) {
    __shared__ int sh[512];
    int t = threadIdx.x;
    int v = (t < NBUK) ? btot[t] : 0;
    sh[t] = v;
    __syncthreads();
#pragma unroll
    for (int o = 1; o < 512; o <<= 1) {
        int u = (t >= o) ? sh[t - o] : 0;
        __syncthreads();
        sh[t] += u;
        __syncthreads();
    }
    if (t < NBUK) bucketbase[t] = sh[t] - v;
    if (t == NBUK - 1) bucketbase[NBUK] = sh[t];
}

// packed record: (src << 8) | (dst & 255)   [src < 2^24; bucket id recovers dst high bits]
__global__ __launch_bounds__(512) void k_partition(const int* __restrict__ src,
                                                   const int* __restrict__ dst, int E, int CHUNK,
                                                   int NBLK, int NBUK,
                                                   const int* __restrict__ blockhist,
                                                   const int* __restrict__ bucketbase,
                                                   unsigned* __restrict__ packed) {
    __shared__ int cur[MAXBUK];
    int t = threadIdx.x, b = blockIdx.x;
    for (int i = t; i < NBUK; i += 512)
        cur[i] = blockhist[(size_t)i * NBLK + b] + bucketbase[i];
    __syncthreads();
    int e0 = b * CHUNK, e1 = e0 + CHUNK; if (e1 > E) e1 = E;
    for (int e = e0 + t; e < e1; e += 512) {
        int d = dst[e], s = src[e];
        int pos = atomicAdd(&cur[d >> BSHIFT], 1);
        packed[pos] = ((unsigned)s << 8) | ((unsigned)d & 255u);
    }
}

__global__ __launch_bounds__(256) void k_fine(const unsigned* __restrict__ packed,
                                              const int* __restrict__ bucketbase,
                                              int* __restrict__ offsets,
                                              int* __restrict__ csr_src,
                                              int N, int NBUK) {
    __shared__ int fcnt[256];
    __shared__ int wsum[4];
    int bucket = blockIdx.x, t = threadIdx.x;
    int lo = bucket << BSHIFT;
    int nn = N - lo; if (nn > 256) nn = 256;
    int ebase = bucketbase[bucket];
    int ecnt = bucketbase[bucket + 1] - ebase;
    fcnt[t] = 0;
    __syncthreads();
    for (int i = t; i < ecnt; i += 256) {
        unsigned p = packed[ebase + i];
        atomicAdd(&fcnt[p & 255u], 1);
    }
    __syncthreads();
    int v = fcnt[t];
    int lane = t & 63, wv = t >> 6;
    int s = v;
#pragma unroll
    for (int o = 1; o < 64; o <<= 1) {
        int u = __shfl_up(s, o, 64);
        if (lane >= o) s += u;
    }
    if (lane == 63) wsum[wv] = s;
    __syncthreads();
    int base = 0;
#pragma unroll
    for (int w = 0; w < 4; ++w) base += (w < wv) ? wsum[w] : 0;
    int excl = s + base - v;
    if (t < nn) offsets[lo + t] = ebase + excl;
    if (bucket == NBUK - 1 && t == 0) offsets[N] = ebase + ecnt;  // == E
    __syncthreads();
    fcnt[t] = excl;   // reuse as cursor
    __syncthreads();
    for (int i = t; i < ecnt; i += 256) {
        unsigned p = packed[ebase + i];
        int pos = atomicAdd(&fcnt[p & 255u], 1);
        csr_src[ebase + pos] = (int)(p >> 8);
    }
}

// ---------------- W2 pre-split: hi/lo bf16, padded 40 -> 48 cols ----------------
__global__ __launch_bounds__(256) void k_splitW2(const float* __restrict__ W2,
                                                 short* __restrict__ w2h,
                                                 short* __restrict__ w2l) {
    int i = blockIdx.x * 256 + threadIdx.x;
    if (i < 64 * 48) {
        int row = i / 48, col = i % 48;
        short hi = 0, lo = 0;
        if (col < 40) splitbf(W2[row * 40 + col], hi, lo);
        w2h[i] = hi; w2l[i] = lo;
    }
}

// ---------------- Layer 1 GEMM via MFMA bf16 (plain; inputs replay-constant) ----------------
__global__ __launch_bounds__(256) void k_gemm1(const float* __restrict__ x,
                                               const float* __restrict__ W1,
                                               const float* __restrict__ att_s,
                                               const float* __restrict__ att_d,
                                               unsigned short* __restrict__ h1b,
                                               float* __restrict__ a_s1,
                                               float* __restrict__ a_d1, int N) {
    int tid = threadIdx.x, wave = tid >> 6, lane = tid & 63;
    int n16 = lane & 15, q = lane >> 4;
    int nb = blockIdx.x * 64 + wave * 16;
    if (nb >= N) return;

    short8 bfr[4][4];
#pragma unroll
    for (int ct = 0; ct < 4; ++ct) {
        int n = ct * 16 + n16;
#pragma unroll
        for (int kc = 0; kc < 4; ++kc) {
            int k0 = kc * 32 + q * 8;
            short8 b;
#pragma unroll
            for (int j = 0; j < 8; ++j) b[j] = f2bf(W1[(k0 + j) * 64 + n]);
            bfr[ct][kc] = b;
        }
    }

    int arow = nb + n16; if (arow >= N) arow = N - 1;
    const float* xr = x + (size_t)arow * 128 + q * 8;
    short8 afr[4];
#pragma unroll
    for (int kc = 0; kc < 4; ++kc) {
        float4 u0 = *(const float4*)(xr + kc * 32);
        float4 u1 = *(const float4*)(xr + kc * 32 + 4);
        short8 a;
        a[0] = f2bf(u0.x); a[1] = f2bf(u0.y); a[2] = f2bf(u0.z); a[3] = f2bf(u0.w);
        a[4] = f2bf(u1.x); a[5] = f2bf(u1.y); a[6] = f2bf(u1.z); a[7] = f2bf(u1.w);
        afr[kc] = a;
    }

    floatx4 acc[4];
#pragma unroll
    for (int ct = 0; ct < 4; ++ct) {
        floatx4 c = {0.f, 0.f, 0.f, 0.f};
#pragma unroll
        for (int kc = 0; kc < 4; ++kc)
            c = __builtin_amdgcn_mfma_f32_16x16x32_bf16(afr[kc], bfr[ct][kc], c, 0, 0, 0);
        acc[ct] = c;
    }

#pragma unroll
    for (int ct = 0; ct < 4; ++ct) {
#pragma unroll
        for (int r = 0; r < 4; ++r) {
            int row = nb + q * 4 + r;
            if (row < N) h1b[(size_t)row * 64 + ct * 16 + n16] = (unsigned short)f2bf(acc[ct][r]);
        }
    }

#pragma unroll
    for (int ct = 0; ct < 4; ++ct) {
        float as = att_s[ct * 16 + n16];
        float ad = att_d[ct * 16 + n16];
#pragma unroll
        for (int r = 0; r < 4; ++r) {
            float ps = acc[ct][r] * as;
            float pd = acc[ct][r] * ad;
#pragma unroll
            for (int m = 1; m < 8; m <<= 1) {
                ps += __shfl_xor(ps, m, 64);
                pd += __shfl_xor(pd, m, 64);
            }
            int row = nb + q * 4 + r;
            if ((n16 & 7) == 0 && row < N) {
                int h = 2 * ct + (n16 >> 3);
                a_s1[row * 8 + h] = ps;
                a_d1[row * 8 + h] = pd;
            }
        }
    }
}

// ---------------- Layer 1 aggregation: R9 pair-scheme (proven 63.5 us) ----------------------
// lane = (q2, c): half q2 processes its own edge; c = channel pair (2c, 2c+1); head = c>>2.
__global__ __launch_bounds__(256) void k_agg1(const unsigned short* __restrict__ h1b,
                                              const float* __restrict__ a_s1,
                                              const float* __restrict__ a_d1,
                                              const int* __restrict__ offsets,
                                              const int* __restrict__ csr_src,
                                              const float* __restrict__ b1,
                                              float* __restrict__ y1, int N) {
    int wave = threadIdx.x >> 6, lane = threadIdx.x & 63;
    int d = blockIdx.x * 4 + wave;
    if (d >= N) return;
    int q2 = lane >> 5;          // which edge of the pair
    int c  = lane & 31;          // channel pair: 2c, 2c+1
    int h  = c >> 2;             // head (same for both channels)
    float ad = a_d1[d * 8 + h];
    float accx = 0.f, accy = 0.f;
    float wsum_l = 0.f;
    if (q2 == 0) {               // self-loop on half 0
        float w0 = lrelu_exp(a_s1[d * 8 + h] + ad);
        unsigned v = *(const unsigned*)(h1b + (size_t)d * 64 + 2 * c);
        accx = w0 * bfpair_lo(v);
        accy = w0 * bfpair_hi(v);
        wsum_l = w0;
    }
    int i0 = offsets[d], i1 = offsets[d + 1];
    for (int base = i0; base < i1; base += 64) {
        int m = i1 - base; if (m > 64) m = 64;
        int sv = (lane < m) ? csr_src[base + lane] : 0;
        for (int j = 0; j < m; j += 16) {
            int   ei[8]; int si[8]; float ev[8]; unsigned vv[8];
#pragma unroll
            for (int u = 0; u < 8; ++u) {
                ei[u] = j + 2 * u + q2;
                si[u] = __shfl(sv, ei[u], 64);
            }
#pragma unroll
            for (int u = 0; u < 8; ++u) ev[u] = a_s1[si[u] * 8 + h] + ad;
#pragma unroll
            for (int u = 0; u < 8; ++u)
                vv[u] = *(const unsigned*)(h1b + (size_t)si[u] * 64 + 2 * c);
#pragma unroll
            for (int u = 0; u < 8; ++u) {
                float w = (ei[u] < m) ? lrelu_exp(ev[u]) : 0.f;
                wsum_l += w;
                accx = fmaf(w, bfpair_lo(vv[u]), accx);
                accy = fmaf(w, bfpair_hi(vv[u]), accy);
            }
        }
    }
    // combine the two halves (edges were split across halves; channels identical)
    accx += __shfl_xor(accx, 32, 64);
    accy += __shfl_xor(accy, 32, 64);
    wsum_l += __shfl_xor(wsum_l, 32, 64);
    if (q2 == 0) {
        float inv = 1.f / (wsum_l + 1e-16f);
        float bx = b1[2 * c], by = b1[2 * c + 1];
        float ox = accx * inv + bx;
        float oy = accy * inv + by;
        ox = ox > 0.f ? ox : expm1f(ox);
        oy = oy > 0.f ? oy : expm1f(oy);
        float2 o2 = make_float2(ox, oy);
        *(float2*)(y1 + (size_t)d * 64 + 2 * c) = o2;   // fp32 (precision-critical)
    }
}

// ---------------- Layer 2 GEMM, split-bf16 (y1 replay-variant -> fp32-class needed) ----------
__global__ __launch_bounds__(256) void k_gemm2(const float* __restrict__ y1,
                                               const short* __restrict__ w2h,
                                               const short* __restrict__ w2l,
                                               const float* __restrict__ att_s,
                                               const float* __restrict__ att_d,
                                               unsigned short* __restrict__ h2b,
                                               float* __restrict__ a2s,
                                               float* __restrict__ a2d, int N) {
    int tid = threadIdx.x, wave = tid >> 6, lane = tid & 63;
    int n16 = lane & 15, q = lane >> 4;
    int nb = blockIdx.x * 64 + wave * 16;
    if (nb >= N) return;

    int arow = nb + n16; if (arow >= N) arow = N - 1;
    const float* yr = y1 + (size_t)arow * 64 + q * 8;
    short8 ah[2], al[2];
#pragma unroll
    for (int kc = 0; kc < 2; ++kc) {
        float4 u0 = *(const float4*)(yr + kc * 32);
        float4 u1 = *(const float4*)(yr + kc * 32 + 4);
        short8 h, l; short hi, lo;
        splitbf(u0.x, hi, lo); h[0] = hi; l[0] = lo;
        splitbf(u0.y, hi, lo); h[1] = hi; l[1] = lo;
        splitbf(u0.z, hi, lo); h[2] = hi; l[2] = lo;
        splitbf(u0.w, hi, lo); h[3] = hi; l[3] = lo;
        splitbf(u1.x, hi, lo); h[4] = hi; l[4] = lo;
        splitbf(u1.y, hi, lo); h[5] = hi; l[5] = lo;
        splitbf(u1.z, hi, lo); h[6] = hi; l[6] = lo;
        splitbf(u1.w, hi, lo); h[7] = hi; l[7] = lo;
        ah[kc] = h; al[kc] = l;
    }

    float psr[4] = {0.f, 0.f, 0.f, 0.f}, pdr[4] = {0.f, 0.f, 0.f, 0.f};
#pragma unroll
    for (int ct = 0; ct < 3; ++ct) {
        int n = ct * 16 + n16;
        short8 bh0, bh1, bl0, bl1;
#pragma unroll
        for (int j = 0; j < 8; ++j) {
            int k0 = q * 8 + j;
            bh0[j] = w2h[k0 * 48 + n];
            bl0[j] = w2l[k0 * 48 + n];
            bh1[j] = w2h[(32 + k0) * 48 + n];
            bl1[j] = w2l[(32 + k0) * 48 + n];
        }
        floatx4 c = {0.f, 0.f, 0.f, 0.f};
        c = __builtin_amdgcn_mfma_f32_16x16x32_bf16(ah[0], bl0, c, 0, 0, 0);
        c = __builtin_amdgcn_mfma_f32_16x16x32_bf16(al[0], bh0, c, 0, 0, 0);
        c = __builtin_amdgcn_mfma_f32_16x16x32_bf16(ah[0], bh0, c, 0, 0, 0);
        c = __builtin_amdgcn_mfma_f32_16x16x32_bf16(ah[1], bl1, c, 0, 0, 0);
        c = __builtin_amdgcn_mfma_f32_16x16x32_bf16(al[1], bh1, c, 0, 0, 0);
        c = __builtin_amdgcn_mfma_f32_16x16x32_bf16(ah[1], bh1, c, 0, 0, 0);

        int col = ct * 16 + n16;
#pragma unroll
        for (int r = 0; r < 4; ++r) {
            int row = nb + q * 4 + r;
            if (col < 40 && row < N) h2b[(size_t)row * 40 + col] = (unsigned short)f2bf(c[r]);
        }
        float asv = (col < 40) ? att_s[col] : 0.f;
        float adv = (col < 40) ? att_d[col] : 0.f;
#pragma unroll
        for (int r = 0; r < 4; ++r) {
            psr[r] = fmaf(c[r], asv, psr[r]);
            pdr[r] = fmaf(c[r], adv, pdr[r]);
        }
    }
#pragma unroll
    for (int r = 0; r < 4; ++r) {
        float ps = psr[r], pd = pdr[r];
#pragma unroll
        for (int m = 1; m < 16; m <<= 1) {
            ps += __shfl_xor(ps, m, 64);
            pd += __shfl_xor(pd, m, 64);
        }
        int row = nb + q * 4 + r;
        if (n16 == 0 && row < N) { a2s[row] = ps; a2d[row] = pd; }
    }
}

// ---------------- Layer 2 aggregation: 3 edges per gather instr + log_softmax ----------------
__global__ __launch_bounds__(256) void k_agg2(const unsigned short* __restrict__ h2b,
                                              const float* __restrict__ a2s,
                                              const float* __restrict__ a2d,
                                              const int* __restrict__ offsets,
                                              const int* __restrict__ csr_src,
                                              const float* __restrict__ b2,
                                              float* __restrict__ out, int N) {
    int wave = threadIdx.x >> 6, lane = threadIdx.x & 63;
    int d = blockIdx.x * 4 + wave;
    if (d >= N) return;
    int t = lane / 20;          // 0..2 active thirds (3 = idle tail lanes 60..63)
    int c = lane % 20;          // channel pair: 2c, 2c+1
    float ad = a2d[d];
    float w0 = lrelu_exp(a2s[d] + ad);
    float accx = 0.f, accy = 0.f;
    if (t == 0) {               // self-loop on third 0
        unsigned v = *(const unsigned*)(h2b + (size_t)d * 40 + 2 * c);
        accx = w0 * bfpair_lo(v);
        accy = w0 * bfpair_hi(v);
    }
    float wsum_l = 0.f;
    int i0 = offsets[d], i1 = offsets[d + 1];
    for (int base = i0; base < i1; base += 48) {
        int m = i1 - base; if (m > 48) m = 48;
        int sv = 0; float wv = 0.f;
        if (lane < m) {
            sv = csr_src[base + lane];
            wv = lrelu_exp(a2s[sv] + ad);
        }
        wsum_l += wv;
        for (int j = 0; j < m; j += 24) {
            int si[8]; float wq[8]; unsigned vv[8];
#pragma unroll
            for (int u = 0; u < 8; ++u) {
                int e = j + 3 * u + t;
                si[u] = __shfl(sv, e, 64);
                wq[u] = __shfl(wv, e, 64);
            }
#pragma unroll
            for (int u = 0; u < 8; ++u)
                vv[u] = *(const unsigned*)(h2b + (size_t)si[u] * 40 + 2 * c);
#pragma unroll
            for (int u = 0; u < 8; ++u) {
                accx = fmaf(wq[u], bfpair_lo(vv[u]), accx);
                accy = fmaf(wq[u], bfpair_hi(vv[u]), accy);
            }
        }
    }
    accx += __shfl(accx, lane + 20, 64) + __shfl(accx, lane + 40, 64);
    accy += __shfl(accy, lane + 20, 64) + __shfl(accy, lane + 40, 64);
#pragma unroll
    for (int mm = 1; mm < 64; mm <<= 1) wsum_l += __shfl_xor(wsum_l, mm, 64);
    float wsum = wsum_l + w0;
    bool act = (lane < 20);
    float inv = 1.f / (wsum + 1e-16f);
    float ox = act ? (accx * inv + b2[2 * c]) : -INFINITY;
    float oy = act ? (accy * inv + b2[2 * c + 1]) : -INFINITY;
    float mx = fmaxf(ox, oy);
#pragma unroll
    for (int mm = 1; mm < 64; mm <<= 1) mx = fmaxf(mx, __shfl_xor(mx, mm, 64));
    float ex = act ? (__expf(ox - mx) + __expf(oy - mx)) : 0.f;
#pragma unroll
    for (int mm = 1; mm < 64; mm <<= 1) ex += __shfl_xor(ex, mm, 64);
    if (act) {
        float lse = __logf(ex);
        float2 o2 = make_float2(ox - mx - lse, oy - mx - lse);
        *(float2*)(out + (size_t)d * 40 + 2 * c) = o2;
    }
}

// ---------------- launcher ----------------

extern "C" void kernel_launch(void* const* d_in, const int* in_sizes, int n_in,
                              void* d_out, int out_size, void* d_ws, size_t ws_size,
                              hipStream_t stream) {
    const float* x   = (const float*)d_in[0];
    const int*   ei  = (const int*)d_in[1];
    const float* W1  = (const float*)d_in[2];
    const float* as1 = (const float*)d_in[3];
    const float* ad1 = (const float*)d_in[4];
    const float* b1  = (const float*)d_in[5];
    const float* W2  = (const float*)d_in[6];
    const float* as2 = (const float*)d_in[7];
    const float* ad2 = (const float*)d_in[8];
    const float* b2  = (const float*)d_in[9];
    float* out = (float*)d_out;

    int N = in_sizes[0] / 128;   // 100000
    int E = in_sizes[1] / 2;     // 1600000
    const int* src = ei;
    const int* dst = ei + E;

    int NBUK = (N + 255) >> BSHIFT;          // 391
    int CHUNK = 4096;
    int NBLK = (E + CHUNK - 1) / CHUNK;      // 391

    char* ws = (char*)d_ws;
    size_t off = 0;
    auto alloc = [&](size_t bytes) -> char* {
        char* p = ws + off;
        off += (bytes + 255) & ~(size_t)255;
        return p;
    };
    unsigned short* h1b = (unsigned short*)alloc((size_t)N * 64 * 2);   // bf16
    float* a_s1    = (float*)alloc((size_t)N * 8 * 4);
    float* a_d1    = (float*)alloc((size_t)N * 8 * 4);
    float* y1      = (float*)alloc((size_t)N * 64 * 4);                 // fp32 (precision-critical)
    // h2b (bf16, 8 MB) and packed (uint, 6.4 MB) are temporally disjoint: share region.
    size_t shared_sz = (size_t)N * 40 * 2;
    if ((size_t)E * 4 > shared_sz) shared_sz = (size_t)E * 4;
    char*  region  = alloc(shared_sz);
    unsigned short* h2b = (unsigned short*)region;
    unsigned* packed    = (unsigned*)region;
    float* a2s     = (float*)alloc((size_t)N * 4);
    float* a2d     = (float*)alloc((size_t)N * 4);
    int*   offsets = (int*)alloc((size_t)(N + 1) * 4);
    int*   csr_src = (int*)alloc((size_t)E * 4);
    int*   blockhist  = (int*)alloc((size_t)NBUK * NBLK * 4);
    int*   btot       = (int*)alloc((size_t)NBUK * 4);
    int*   bucketbase = (int*)alloc((size_t)(NBUK + 1) * 4);
    short* w2h     = (short*)alloc((size_t)64 * 48 * 2);
    short* w2l     = (short*)alloc((size_t)64 * 48 * 2);

    int nb = (N + 3) / 4;
    int gb = (N + 63) / 64;

    k_hist<<<NBLK, 512, 0, stream>>>(dst, E, CHUNK, NBLK, NBUK, blockhist);
    k_colscan<<<NBUK, 256, 0, stream>>>(blockhist, btot, NBLK);
    k_bucket_scan<<<1, 512, 0, stream>>>(btot, bucketbase, NBUK);
    k_partition<<<NBLK, 512, 0, stream>>>(src, dst, E, CHUNK, NBLK, NBUK, blockhist,
                                          bucketbase, packed);
    k_fine<<<NBUK, 256, 0, stream>>>(packed, bucketbase, offsets, csr_src, N, NBUK);
    k_splitW2<<<12, 256, 0, stream>>>(W2, w2h, w2l);
    k_gemm1<<<gb, 256, 0, stream>>>(x, W1, as1, ad1, h1b, a_s1, a_d1, N);
    k_agg1<<<nb, 256, 0, stream>>>(h1b, a_s1, a_d1, offsets, csr_src, b1, y1, N);
    k_gemm2<<<gb, 256, 0, stream>>>(y1, w2h, w2l, as2, ad2, h2b, a2s, a2d, N);
    k_agg2<<<nb, 256, 0, stream>>>(h2b, a2s, a2d, offsets, csr_src, b2, out, N);
}